// Round 6
// baseline (475.208 us; speedup 1.0000x reference)
//
#include <hip/hip_runtime.h>
#include <math.h>

typedef _Float16 f16;
typedef _Float16 f16x8 __attribute__((ext_vector_type(8)));
typedef float f32x4 __attribute__((ext_vector_type(4)));
typedef unsigned long long u64;

#define LDIM 128
#define HOUT 256

__device__ __forceinline__ float tanh_fast(float x) {
    float a = fabsf(x);
    float e = __expf(-2.0f * a);
    float r = (1.0f - e) / (1.0f + e);
    return copysignf(r, x);
}

// LLC-coherent (agent-scope, relaxed) accessors: sc1 ops, no L2 inv/wb
__device__ __forceinline__ void  st_agent(float* p, float v) {
    __hip_atomic_store(p, v, __ATOMIC_RELAXED, __HIP_MEMORY_SCOPE_AGENT);
}
__device__ __forceinline__ float ld_agent(const float* p) {
    return __hip_atomic_load(p, __ATOMIC_RELAXED, __HIP_MEMORY_SCOPE_AGENT);
}
__device__ __forceinline__ u64   ld_agent64(const u64* p) {
    return __hip_atomic_load(p, __ATOMIC_RELAXED, __HIP_MEMORY_SCOPE_AGENT);
}
__device__ __forceinline__ unsigned ld_flag(const unsigned* p) {
    return __hip_atomic_load(p, __ATOMIC_RELAXED, __HIP_MEMORY_SCOPE_AGENT);
}

// wt_i: [k][h][c] f16  <- W_i[h][c][k]
// wt2h packed A-frags: wt2h[(((s*8+kk)*16+h16)*64+lane)*8+j] = W_h[h16*16+(lane&15)][kk*32+(lane>>4)*8+j][s]
__global__ void prep_w(const float* __restrict__ wi, f16* __restrict__ wti,
                       const float* __restrict__ wh, f16* __restrict__ wt2h)
{
    int idx = blockIdx.x * 256 + threadIdx.x;
    const int ni = 3 * HOUT * 128;
    if (idx < ni) {
        int k = idx / (HOUT * 128);
        int r = idx - k * (HOUT * 128);
        int h = r >> 7, c = r & 127;
        wti[idx] = (f16)wi[(h * 128 + c) * 3 + k];
    } else {
        int e = idx - ni;
        if (e >= 3 * HOUT * 256) return;
        int j    = e & 7;
        int lane = (e >> 3) & 63;
        int h16  = (e >> 9) & 15;
        int kk   = (e >> 13) & 7;
        int s    = e >> 16;
        int hh = h16 * 16 + (lane & 15);
        int c  = kk * 32 + (lane >> 4) * 8 + j;
        wt2h[e] = (f16)wh[(hh * 256 + c) * 3 + s];
    }
}

// ---------------- Phase 1: Z[n] = conv_i(x[n]), all n parallel (XCD-clustered) ----------------
__global__ __launch_bounds__(256, 4)
void conv_i_all(const float* __restrict__ x, const f16* __restrict__ wt,
                float* __restrict__ out)
{
    __shared__ __align__(16) char smem[33792];
    const int tid = threadIdx.x;
    const int lane = tid & 63, wid = tid >> 6;
    const int wh = wid >> 1, wl = wid & 1;
    const int n   = blockIdx.x & 1023;
    const int sub = blockIdx.x >> 10;
    const int h0  = (sub >> 1) * 64;
    const int Lb  = (sub & 1) * 64;
    const int l16 = lane & 15, g = lane >> 4;

    const float* actn = x + (long)n * (128 * LDIM);

    {
        const int c4 = tid >> 4;
        const int rb = tid & 15;
        const int lg = Lb + rb * 4;
        f32x4 v[8];
#pragma unroll
        for (int ci = 0; ci < 8; ++ci)
            v[ci] = *(const f32x4*)(actn + (c4 * 8 + ci) * LDIM + lg);
#pragma unroll
        for (int i = 0; i < 4; ++i) {
            int r = rb * 4 + i + 1;
            f16x8 hi, lo;
#pragma unroll
            for (int ci = 0; ci < 8; ++ci) {
                float xx = v[ci][i];
                f16 h = (f16)xx;
                hi[ci] = h;
                lo[ci] = (f16)(xx - (float)h);
            }
            int base = r * 256 + ((c4 ^ (r & 7)) << 4);
            *(f16x8*)(smem + base) = hi;
            *(f16x8*)(smem + 16896 + base) = lo;
        }
        int cl = tid & 127, e = tid >> 7;
        int r = e ? 65 : 0;
        int lg2 = Lb + r - 1;
        float xx = ((unsigned)lg2 < 128u) ? actn[cl * LDIM + lg2] : 0.f;
        f16 h = (f16)xx;
        f16 lo = (f16)(xx - (float)h);
        int off = r * 256 + ((((cl >> 3) ^ (r & 7)) << 4)) + (cl & 7) * 2;
        *(f16*)(smem + off) = h;
        *(f16*)(smem + 16896 + off) = lo;
    }
    __syncthreads();

    f32x4 acc[2][2] = {};
#pragma unroll
    for (int kk = 0; kk < 4; ++kk) {
        f16x8 afr[3][2];
#pragma unroll
        for (int s = 0; s < 3; ++s)
#pragma unroll
            for (int hf = 0; hf < 2; ++hf) {
                int hh = h0 + wh * 32 + hf * 16 + l16;
                afr[s][hf] = *(const f16x8*)(wt + ((s * HOUT + hh) << 7) + kk * 32 + g * 8);
            }
#pragma unroll
        for (int s = 0; s < 3; ++s) {
            f16x8 bfr[2][2];
#pragma unroll
            for (int lf = 0; lf < 2; ++lf) {
                int r = wl * 32 + lf * 16 + l16 + s;
                int base = r * 256 + ((((kk * 4 + g) ^ (r & 7)) << 4));
                bfr[lf][0] = *(const f16x8*)(smem + base);
                bfr[lf][1] = *(const f16x8*)(smem + 16896 + base);
            }
#pragma unroll
            for (int hf = 0; hf < 2; ++hf)
#pragma unroll
                for (int lf = 0; lf < 2; ++lf) {
                    acc[hf][lf] = __builtin_amdgcn_mfma_f32_16x16x32_f16(
                        afr[s][hf], bfr[lf][0], acc[hf][lf], 0, 0, 0);
                    acc[hf][lf] = __builtin_amdgcn_mfma_f32_16x16x32_f16(
                        afr[s][hf], bfr[lf][1], acc[hf][lf], 0, 0, 0);
                }
        }
    }

    float* outn = out + (long)n * (HOUT * LDIM);
#pragma unroll
    for (int hf = 0; hf < 2; ++hf)
#pragma unroll
        for (int lf = 0; lf < 2; ++lf)
#pragma unroll
            for (int vv = 0; vv < 4; ++vv) {
                int hh = h0 + wh * 32 + hf * 16 + g * 4 + vv;
                int ll = Lb + wl * 32 + lf * 16 + l16;
                outn[hh * LDIM + ll] = acc[hf][lf][vv];
            }
}

// ---------------- Phase 2: persistent recurrence, 2 chains/CU, flag-array sync ----------------
// grid 512, 128 threads (2 waves). b = bid>>5 (co-resident pair bid/bid+256 -> different b),
// sub = bid&31: h0idx = sub>>3 (64h), lbidx = sub&7 (16l). Wave tile 32h x 16l.
// LDS: [pl=2][r=0..17][c=0..255] f16, row 512 B, plane 9216 B, 16B-granule XOR swizzle.
// Sync: flag[b*64+sub] = t+1 published after barrier-drain; wave0 lanes 0-11 poll the 12 deps.
__global__ __launch_bounds__(128, 1)
void rnn_persist(const f16* __restrict__ wt2, float* __restrict__ out,
                 unsigned* __restrict__ flags)
{
    __shared__ __align__(16) char smem[18432];
    const int tid  = threadIdx.x;
    const int lane = tid & 63, wid = tid >> 6;   // 2 waves
    const int wh   = wid;
    const int bid  = blockIdx.x;
    const int b    = bid >> 5;
    const int sub  = bid & 31;
    const int h0i  = sub >> 3;     // 0..3
    const int lbi  = sub & 7;      // 0..7
    const int h0   = h0i * 64;
    const int Lb   = lbi * 16;
    const int l16  = lane & 15, g = lane >> 4;
    const long HL  = (long)HOUT * LDIM;
    float* outb = out + (long)b * (64 * HL);
    unsigned* fb = flags + b * 64;

    // ---- weights into registers, once
    f16x8 afr[3][8][2];
#pragma unroll
    for (int s = 0; s < 3; ++s)
#pragma unroll
        for (int kk = 0; kk < 8; ++kk)
#pragma unroll
            for (int hf = 0; hf < 2; ++hf) {
                int h16 = h0i * 4 + wh * 2 + hf;
                afr[s][kk][hf] = *(const f16x8*)(wt2 +
                    ((((s * 8 + kk) * 16 + h16) * 64 + lane) << 3));
            }

    // ---- dependency table for wave-0 poll lanes (12 deps; out-of-range -> self)
    int dep = sub;
    if (lane < 12) {
        int hp = lane & 3;
        int d  = lane >> 2;            // 0: same Lb, 1: Lb-16, 2: Lb+16
        int lb2 = lbi + (d == 1 ? -1 : (d == 2 ? 1 : 0));
        if (lb2 < 0 || lb2 > 7) { hp = h0i; lb2 = lbi; }
        dep = hp * 8 + lb2;
    }

    // ---- t = 0: h_0 = tanh(Z_0), in place
#pragma unroll
    for (int hf = 0; hf < 2; ++hf)
#pragma unroll
        for (int vv = 0; vv < 4; ++vv) {
            int hh = h0 + wh * 32 + hf * 16 + g * 4 + vv;
            long idx = (long)hh * LDIM + Lb + l16;
            st_agent(&outb[idx], tanh_fast(outb[idx]));
        }
    __syncthreads();                       // both waves' sc1 stores drained
    if (tid == 0)
        __hip_atomic_store(&fb[sub], 1u, __ATOMIC_RELAXED, __HIP_MEMORY_SCOPE_AGENT);

    for (int t = 1; t < 64; ++t) {
        float* outt = outb + (long)t * HL;
        const float* prev = outb + (long)(t - 1) * HL;

        // prefetch Z_t (own tile, untouched by anyone else before this block's epilogue)
        float zreg[2][4];
#pragma unroll
        for (int hf = 0; hf < 2; ++hf)
#pragma unroll
            for (int vv = 0; vv < 4; ++vv) {
                int hh = h0 + wh * 32 + hf * 16 + g * 4 + vv;
                zreg[hf][vv] = outt[(long)hh * LDIM + Lb + l16];
            }

        // ---- wave 0 polls the 12 deps for step t (flag >= t)
        if (wid == 0) {
            unsigned v = (lane < 12) ? ld_flag(&fb[dep]) : 0xFFFFFFFFu;
            while (__any(v < (unsigned)t)) {
                __builtin_amdgcn_s_sleep(1);
                if (lane < 12) v = ld_flag(&fb[dep]);
            }
        }
        __syncthreads();
        asm volatile("" ::: "memory");

        // ---- stage h_{t-1}[256c][Lb-1..Lb+16] -> LDS hi/lo (sc1 u64 loads)
        {
            const int cg = tid >> 2;       // 32 c-groups of 8
            const int lq = tid & 3;        // 4 l-quads of 4
            const int lg = Lb + lq * 4;
            f32x4 v[8];
#pragma unroll
            for (int ci = 0; ci < 8; ++ci) {
                const u64* p = (const u64*)(prev + (cg * 8 + ci) * LDIM + lg);
                u64 a  = ld_agent64(p);
                u64 bq = ld_agent64(p + 1);
                v[ci][0] = __uint_as_float((unsigned)a);
                v[ci][1] = __uint_as_float((unsigned)(a >> 32));
                v[ci][2] = __uint_as_float((unsigned)bq);
                v[ci][3] = __uint_as_float((unsigned)(bq >> 32));
            }
#pragma unroll
            for (int i = 0; i < 4; ++i) {
                int r = lq * 4 + i + 1;    // rows 1..16
                f16x8 hi, lo;
#pragma unroll
                for (int ci = 0; ci < 8; ++ci) {
                    float xx = v[ci][i];
                    f16 h = (f16)xx;
                    hi[ci] = h;
                    lo[ci] = (f16)(xx - (float)h);
                }
                int base = r * 512 + ((cg ^ (r & 7)) << 4);
                *(f16x8*)(smem + base) = hi;
                *(f16x8*)(smem + 9216 + base) = lo;
            }
            // edge rows r=0 (l=Lb-1), r=17 (l=Lb+16)
#pragma unroll
            for (int e = 0; e < 2; ++e) {
                int r = e ? 17 : 0;
                int lg2 = Lb + (e ? 16 : -1);
#pragma unroll
                for (int half = 0; half < 2; ++half) {
                    int c = tid + half * 128;
                    float xx = ((unsigned)lg2 < 128u) ? ld_agent(&prev[c * LDIM + lg2]) : 0.f;
                    f16 h = (f16)xx;
                    f16 lo = (f16)(xx - (float)h);
                    int off = r * 512 + ((((c >> 3) ^ (r & 7)) << 4)) + (c & 7) * 2;
                    *(f16*)(smem + off) = h;
                    *(f16*)(smem + 9216 + off) = lo;
                }
            }
        }
        __syncthreads();

        // ---- compute: 8 kk x 3 s x 2 planes x 2 hf MFMAs per wave
        f32x4 acc[2] = {};
#pragma unroll
        for (int kk = 0; kk < 8; ++kk)
#pragma unroll
            for (int s = 0; s < 3; ++s) {
                int r = l16 + s;
                int base = r * 512 + ((((kk * 4 + g) ^ (r & 7)) << 4));
                f16x8 b0 = *(const f16x8*)(smem + base);
                f16x8 b1 = *(const f16x8*)(smem + 9216 + base);
#pragma unroll
                for (int hf = 0; hf < 2; ++hf) {
                    acc[hf] = __builtin_amdgcn_mfma_f32_16x16x32_f16(
                        afr[s][kk][hf], b0, acc[hf], 0, 0, 0);
                    acc[hf] = __builtin_amdgcn_mfma_f32_16x16x32_f16(
                        afr[s][kk][hf], b1, acc[hf], 0, 0, 0);
                }
            }

        // ---- epilogue: h_t = tanh(conv + Z_t)
#pragma unroll
        for (int hf = 0; hf < 2; ++hf)
#pragma unroll
            for (int vv = 0; vv < 4; ++vv) {
                int hh = h0 + wh * 32 + hf * 16 + g * 4 + vv;
                st_agent(&outt[(long)hh * LDIM + Lb + l16],
                         tanh_fast(acc[hf][vv] + zreg[hf][vv]));
            }

        __syncthreads();                   // both waves' stores drained at LLC
        if (tid == 0)
            __hip_atomic_store(&fb[sub], (unsigned)(t + 1),
                               __ATOMIC_RELAXED, __HIP_MEMORY_SCOPE_AGENT);
    }
}

extern "C" void kernel_launch(void* const* d_in, const int* in_sizes, int n_in,
                              void* d_out, int out_size, void* d_ws, size_t ws_size,
                              hipStream_t stream)
{
    const float* x   = (const float*)d_in[0];   // [16][64][128][128]
    const float* W_i = (const float*)d_in[1];   // [256][128][3]
    const float* W_h = (const float*)d_in[2];   // [256][256][3]
    float* out = (float*)d_out;                 // [16][64][256][128]

    f16* wt_i  = (f16*)d_ws;                                 // 196608 B
    f16* wt2_h = (f16*)((char*)d_ws + 196608);               // 393216 B
    unsigned* flags = (unsigned*)((char*)d_ws + 589824);     // 16*64*4 = 4096 B

    prep_w<<<1152, 256, 0, stream>>>(W_i, wt_i, W_h, wt2_h);
    hipMemsetAsync(flags, 0, 4096, stream);

    conv_i_all<<<8192, 256, 0, stream>>>(x, wt_i, out);
    rnn_persist<<<512, 128, 0, stream>>>(wt2_h, out, flags);
}

// Round 7
// 403.858 us; speedup vs baseline: 1.1767x; 1.1767x over previous
//
#include <hip/hip_runtime.h>
#include <math.h>

typedef _Float16 f16;
typedef _Float16 f16x2 __attribute__((ext_vector_type(2)));
typedef _Float16 f16x8 __attribute__((ext_vector_type(8)));
typedef float f32x4 __attribute__((ext_vector_type(4)));

#define LDIM 128
#define HOUT 256

__device__ __forceinline__ float tanh_fast(float x) {
    float a = fabsf(x);
    float e = __expf(-2.0f * a);
    float r = (1.0f - e) / (1.0f + e);
    return copysignf(r, x);
}

// LLC-coherent (agent-scope, relaxed) accessors: sc1 ops, no L2 inv/wb
__device__ __forceinline__ void  st_agent(float* p, float v) {
    __hip_atomic_store(p, v, __ATOMIC_RELAXED, __HIP_MEMORY_SCOPE_AGENT);
}
__device__ __forceinline__ float ld_agent(const float* p) {
    return __hip_atomic_load(p, __ATOMIC_RELAXED, __HIP_MEMORY_SCOPE_AGENT);
}

// wt_i: [k][h][c] f16  <- W_i[h][c][k]
// wt2h packed A-frags: wt2h[(((s*8+kk)*16+h16)*64+lane)*8+j] = W_h[h16*16+(lane&15)][kk*32+(lane>>4)*8+j][s]
__global__ void prep_w(const float* __restrict__ wi, f16* __restrict__ wti,
                       const float* __restrict__ wh, f16* __restrict__ wt2h)
{
    int idx = blockIdx.x * 256 + threadIdx.x;
    const int ni = 3 * HOUT * 128;
    if (idx < ni) {
        int k = idx / (HOUT * 128);
        int r = idx - k * (HOUT * 128);
        int h = r >> 7, c = r & 127;
        wti[idx] = (f16)wi[(h * 128 + c) * 3 + k];
    } else {
        int e = idx - ni;
        if (e >= 3 * HOUT * 256) return;
        int j    = e & 7;
        int lane = (e >> 3) & 63;
        int h16  = (e >> 9) & 15;
        int kk   = (e >> 13) & 7;
        int s    = e >> 16;
        int hh = h16 * 16 + (lane & 15);
        int c  = kk * 32 + (lane >> 4) * 8 + j;
        wt2h[e] = (f16)wh[(hh * 256 + c) * 3 + s];
    }
}

// ---------------- Phase 1: Z[n] = conv_i(x[n]), all n parallel (XCD-clustered) ----------------
__global__ __launch_bounds__(256, 4)
void conv_i_all(const float* __restrict__ x, const f16* __restrict__ wt,
                float* __restrict__ out)
{
    __shared__ __align__(16) char smem[33792];
    const int tid = threadIdx.x;
    const int lane = tid & 63, wid = tid >> 6;
    const int wh = wid >> 1, wl = wid & 1;
    const int n   = blockIdx.x & 1023;
    const int sub = blockIdx.x >> 10;
    const int h0  = (sub >> 1) * 64;
    const int Lb  = (sub & 1) * 64;
    const int l16 = lane & 15, g = lane >> 4;

    const float* actn = x + (long)n * (128 * LDIM);

    {
        const int c4 = tid >> 4;
        const int rb = tid & 15;
        const int lg = Lb + rb * 4;
        f32x4 v[8];
#pragma unroll
        for (int ci = 0; ci < 8; ++ci)
            v[ci] = *(const f32x4*)(actn + (c4 * 8 + ci) * LDIM + lg);
#pragma unroll
        for (int i = 0; i < 4; ++i) {
            int r = rb * 4 + i + 1;
            f16x8 hi, lo;
#pragma unroll
            for (int ci = 0; ci < 8; ++ci) {
                float xx = v[ci][i];
                f16 h = (f16)xx;
                hi[ci] = h;
                lo[ci] = (f16)(xx - (float)h);
            }
            int base = r * 256 + ((c4 ^ (r & 7)) << 4);
            *(f16x8*)(smem + base) = hi;
            *(f16x8*)(smem + 16896 + base) = lo;
        }
        int cl = tid & 127, e = tid >> 7;
        int r = e ? 65 : 0;
        int lg2 = Lb + r - 1;
        float xx = ((unsigned)lg2 < 128u) ? actn[cl * LDIM + lg2] : 0.f;
        f16 h = (f16)xx;
        f16 lo = (f16)(xx - (float)h);
        int off = r * 256 + ((((cl >> 3) ^ (r & 7)) << 4)) + (cl & 7) * 2;
        *(f16*)(smem + off) = h;
        *(f16*)(smem + 16896 + off) = lo;
    }
    __syncthreads();

    f32x4 acc[2][2] = {};
#pragma unroll
    for (int kk = 0; kk < 4; ++kk) {
        f16x8 afr[3][2];
#pragma unroll
        for (int s = 0; s < 3; ++s)
#pragma unroll
            for (int hf = 0; hf < 2; ++hf) {
                int hh = h0 + wh * 32 + hf * 16 + l16;
                afr[s][hf] = *(const f16x8*)(wt + ((s * HOUT + hh) << 7) + kk * 32 + g * 8);
            }
#pragma unroll
        for (int s = 0; s < 3; ++s) {
            f16x8 bfr[2][2];
#pragma unroll
            for (int lf = 0; lf < 2; ++lf) {
                int r = wl * 32 + lf * 16 + l16 + s;
                int base = r * 256 + ((((kk * 4 + g) ^ (r & 7)) << 4));
                bfr[lf][0] = *(const f16x8*)(smem + base);
                bfr[lf][1] = *(const f16x8*)(smem + 16896 + base);
            }
#pragma unroll
            for (int hf = 0; hf < 2; ++hf)
#pragma unroll
                for (int lf = 0; lf < 2; ++lf) {
                    acc[hf][lf] = __builtin_amdgcn_mfma_f32_16x16x32_f16(
                        afr[s][hf], bfr[lf][0], acc[hf][lf], 0, 0, 0);
                    acc[hf][lf] = __builtin_amdgcn_mfma_f32_16x16x32_f16(
                        afr[s][hf], bfr[lf][1], acc[hf][lf], 0, 0, 0);
                }
        }
    }

    float* outn = out + (long)n * (HOUT * LDIM);
#pragma unroll
    for (int hf = 0; hf < 2; ++hf)
#pragma unroll
        for (int lf = 0; lf < 2; ++lf)
#pragma unroll
            for (int vv = 0; vv < 4; ++vv) {
                int hh = h0 + wh * 32 + hf * 16 + g * 4 + vv;
                int ll = Lb + wl * 32 + lf * 16 + l16;
                outn[hh * LDIM + ll] = acc[hf][lf][vv];
            }
}

// ---------------- Phase 2: persistent recurrence, L-split only ----------------
// 128 blocks = 16 b x 8 l-windows (16 cols each); 512 thr = 8 waves, wave owns 32 h.
// Each block computes ALL 256 h for its window -> cross-block dep = 2 halo columns only.
// h_t written directly into next step's LDS B-panel (double-buffered); no LLC staging read.
// LDS panel: [plane 2][row 18][c 256] f16; row = l-1-l0+1 (r0/r17 = halos); 16B-granule XOR swizzle.
__global__ __launch_bounds__(512, 2)
void rnn_persist(const f16* __restrict__ wt2, float* __restrict__ out,
                 unsigned* __restrict__ flags)
{
    __shared__ __align__(16) char smem[36864];   // 2 panels x 18432 B
    const int tid  = threadIdx.x;
    const int lane = tid & 63, wid = tid >> 6;   // 8 waves
    const int b    = blockIdx.x & 15;
    const int lw   = blockIdx.x >> 4;            // 0..7
    const int l0   = lw * 16;
    const int l16  = lane & 15, g = lane >> 4;
    const long HL  = (long)HOUT * LDIM;
    float* outb    = out + (long)b * (64 * HL);

    // poll targets: lane0 -> left neighbor, lane1 -> right (self if edge => always satisfied)
    int deplw = lw;
    if (lane == 0 && lw > 0) deplw = lw - 1;
    if (lane == 1 && lw < 7) deplw = lw + 1;
    const unsigned* depflag = &flags[(b * 8 + deplw) * 16];
    unsigned* myflag = &flags[(b * 8 + lw) * 16];

    // ---- A-frags (weights) into registers once: wave's 32 h -> h16 = wid*2 + hf
    f16x8 afr[3][8][2];
#pragma unroll
    for (int s = 0; s < 3; ++s)
#pragma unroll
        for (int kk = 0; kk < 8; ++kk)
#pragma unroll
            for (int hf = 0; hf < 2; ++hf) {
                int h16 = wid * 2 + hf;
                afr[s][kk][hf] = *(const f16x8*)(wt2 +
                    ((((s * 8 + kk) * 16 + h16) * 64 + lane) << 3));
            }

    for (int t = 0; t < 64; ++t) {
        float* outt = outb + (long)t * HL;

        // prefetch Z_t (own tile; nobody else touches it) - normal loads, overlap poll
        float z[2][4];
#pragma unroll
        for (int hf = 0; hf < 2; ++hf)
#pragma unroll
            for (int vv = 0; vv < 4; ++vv) {
                int c = wid * 32 + hf * 16 + g * 4 + vv;
                z[hf][vv] = outt[(long)c * LDIM + l0 + l16];
            }

        f32x4 acc[2] = {};
        if (t > 0) {
            const float* prev = outt - HL;

            // ---- poll neighbors finished step t-1 (each wave independently, lanes 0/1)
            {
                unsigned v = (lane < 2)
                    ? __hip_atomic_load(depflag, __ATOMIC_RELAXED, __HIP_MEMORY_SCOPE_AGENT)
                    : 0xFFFFFFFFu;
                while (__any(v < (unsigned)t)) {
                    __builtin_amdgcn_s_sleep(1);
                    if (lane < 2)
                        v = __hip_atomic_load(depflag, __ATOMIC_RELAXED, __HIP_MEMORY_SCOPE_AGENT);
                }
            }
            asm volatile("" ::: "memory");

            // ---- halo columns of h_{t-1} -> read panel rows 0 / 17 (sc1 loads)
            char* pr = smem + ((t - 1) & 1) * 18432;
            if (tid < 256) {
                int c = tid;
                float xx = (lw > 0) ? ld_agent(&prev[(long)c * LDIM + l0 - 1]) : 0.f;
                f16 h = (f16)xx, lo = (f16)(xx - (float)h);
                int off = ((c >> 3) << 4) + (c & 7) * 2;                     // r=0, r&7=0
                *(f16*)(pr + off) = h;
                *(f16*)(pr + 9216 + off) = lo;
            } else {
                int c = tid - 256;
                float xx = (lw < 7) ? ld_agent(&prev[(long)c * LDIM + l0 + 16]) : 0.f;
                f16 h = (f16)xx, lo = (f16)(xx - (float)h);
                int off = 17 * 512 + ((((c >> 3) ^ 1) << 4)) + (c & 7) * 2;  // r=17, r&7=1
                *(f16*)(pr + off) = h;
                *(f16*)(pr + 9216 + off) = lo;
            }
            __syncthreads();

            // ---- conv from read panel: 8 kk x 3 s x 2 planes x 2 hf
#pragma unroll
            for (int kk = 0; kk < 8; ++kk)
#pragma unroll
                for (int s = 0; s < 3; ++s) {
                    int r = l16 + s;
                    int base = r * 512 + ((((kk * 4 + g) ^ (r & 7)) << 4));
                    f16x8 b0 = *(const f16x8*)(pr + base);
                    f16x8 b1 = *(const f16x8*)(pr + 9216 + base);
#pragma unroll
                    for (int hf = 0; hf < 2; ++hf) {
                        acc[hf] = __builtin_amdgcn_mfma_f32_16x16x32_f16(
                            afr[s][kk][hf], b0, acc[hf], 0, 0, 0);
                        acc[hf] = __builtin_amdgcn_mfma_f32_16x16x32_f16(
                            afr[s][kk][hf], b1, acc[hf], 0, 0, 0);
                    }
                }
        }

        // ---- epilogue: h_t = tanh(acc + Z_t); sc1 global stores + write-panel rows 1..16
        char* pw = smem + (t & 1) * 18432;
        const int r  = l16 + 1;
        const int rx = r & 7;
#pragma unroll
        for (int hf = 0; hf < 2; ++hf) {
            float hv[4];
#pragma unroll
            for (int vv = 0; vv < 4; ++vv) {
                int c = wid * 32 + hf * 16 + g * 4 + vv;
                hv[vv] = tanh_fast(acc[hf][vv] + z[hf][vv]);
                st_agent(&outt[(long)c * LDIM + l0 + l16], hv[vv]);
            }
#pragma unroll
            for (int p = 0; p < 2; ++p) {
                int c = wid * 32 + hf * 16 + g * 4 + p * 2;
                float a0 = hv[2 * p], a1 = hv[2 * p + 1];
                f16 h0 = (f16)a0, h1 = (f16)a1;
                f16 e0 = (f16)(a0 - (float)h0), e1 = (f16)(a1 - (float)h1);
                int off = r * 512 + ((((c >> 3) ^ rx) << 4)) + (c & 7) * 2;
                f16x2 hw; hw[0] = h0; hw[1] = h1;
                f16x2 ew; ew[0] = e0; ew[1] = e1;
                *(f16x2*)(pw + off) = hw;
                *(f16x2*)(pw + 9216 + off) = ew;
            }
        }
        __syncthreads();   // all waves: sc1 stores drained (barrier waits vmcnt), LDS visible
        if (tid == 0)
            __hip_atomic_store(myflag, (unsigned)(t + 1),
                               __ATOMIC_RELAXED, __HIP_MEMORY_SCOPE_AGENT);
    }
}

extern "C" void kernel_launch(void* const* d_in, const int* in_sizes, int n_in,
                              void* d_out, int out_size, void* d_ws, size_t ws_size,
                              hipStream_t stream)
{
    const float* x   = (const float*)d_in[0];   // [16][64][128][128]
    const float* W_i = (const float*)d_in[1];   // [256][128][3]
    const float* W_h = (const float*)d_in[2];   // [256][256][3]
    float* out = (float*)d_out;                 // [16][64][256][128]

    f16* wt_i  = (f16*)d_ws;                                 // 196608 B
    f16* wt2_h = (f16*)((char*)d_ws + 196608);               // 393216 B
    unsigned* flags = (unsigned*)((char*)d_ws + 589824);     // 16*8*16*4 = 8192 B

    prep_w<<<1152, 256, 0, stream>>>(W_i, wt_i, W_h, wt2_h);
    hipMemsetAsync(flags, 0, 8192, stream);

    conv_i_all<<<8192, 256, 0, stream>>>(x, wt_i, out);
    rnn_persist<<<128, 512, 0, stream>>>(wt2_h, out, flags);
}